// Round 1
// baseline (98.822 us; speedup 1.0000x reference)
//
#include <hip/hip_runtime.h>
#include <cstdint>
#include <cstddef>

namespace {

constexpr int TIL = 8;
constexpr int WID = 512;
constexpr int HEI = 512;
constexpr int NB  = 16;
constexpr int TPR = WID / TIL;        // 64 tiles per 8-row strip
constexpr int LSTRIDE = 65;           // padded per-tile stride (floats) -> conflict-free
constexpr int CH = TPR * LSTRIDE;     // 4160 floats per channel per strip

// cos(t * pi/16) lookup, exact to fp32
constexpr float C16[17] = {
  1.0f, 0.9807852804032304f, 0.9238795325112867f, 0.8314696123025452f,
  0.7071067811865476f, 0.5555702330196022f, 0.3826834323650898f,
  0.1950903220161283f, 0.0f, -0.1950903220161283f, -0.3826834323650898f,
  -0.5555702330196022f, -0.7071067811865476f, -0.8314696123025452f,
  -0.9238795325112867f, -0.9807852804032304f, -1.0f
};

constexpr float cosp(int t) {         // cos(t*pi/16), any integer t
  int a = ((t % 32) + 32) % 32;
  return (a <= 16) ? C16[a] : C16[32 - a];
}

struct Tbl { float D[8][8]; float ID[8][8]; };

constexpr Tbl make_tbl() {
  Tbl t{};
  for (int k = 0; k < 8; ++k)
    for (int n = 0; n < 8; ++n) {
      // D[k][n] = cos(pi/8 * (n+0.5) * k) = cos((2n+1)k * pi/16)
      t.D[k][n] = cosp((2 * n + 1) * k);
      // ID[k][n] = ((n==0)*(-0.5) + cos(pi/8*(k+0.5)*n)) * 0.25
      float v = cosp((2 * k + 1) * n);
      if (n == 0) v -= 0.5f;
      t.ID[k][n] = v * 0.25f;
    }
  return t;
}

constexpr Tbl TBL = make_tbl();

// zigzag keep masks: Y keeps 25, U/V keep 9 coefficients
constexpr bool keptY(int k, int l) { return (k + l <= 5) || (k + l == 6 && l <= 3); }
constexpr bool keptC(int k, int l) { return (k + l <= 2) || (k + l == 3 && k <= 2); }

// In-place 8x8: X -> ID @ (mask .* (D @ X @ D^T)) @ ID^T
// Exploits mask sparsity: Y channel needs only rows 0..6 of D@X, UV only 0..2.
template <bool ISY>
__device__ __forceinline__ void tile_transform(float* __restrict__ t) {
  constexpr int KM = ISY ? 7 : 3;

  float T[KM][8];                      // T = D @ X, rows 0..KM-1
#pragma unroll
  for (int k = 0; k < KM; ++k)
#pragma unroll
    for (int m = 0; m < 8; ++m) T[k][m] = 0.0f;

#pragma unroll
  for (int n = 0; n < 8; ++n) {
    float x[8];
#pragma unroll
    for (int m = 0; m < 8; ++m) x[m] = t[n * 8 + m];
#pragma unroll
    for (int k = 0; k < KM; ++k) {
      const float d = TBL.D[k][n];
#pragma unroll
      for (int m = 0; m < 8; ++m) T[k][m] += d * x[m];
    }
  }

  float Yv[KM][8];                     // masked DCT coefficients
#pragma unroll
  for (int k = 0; k < KM; ++k)
#pragma unroll
    for (int l = 0; l < 8; ++l) {
      const bool kept = ISY ? keptY(k, l) : keptC(k, l);
      if (kept) {
        float s = 0.0f;
#pragma unroll
        for (int m = 0; m < 8; ++m) s += T[k][m] * TBL.D[l][m];
        Yv[k][l] = s;
      }
    }

  float Uv[KM][8];                     // U = Yv @ ID^T (restricted to kept l)
#pragma unroll
  for (int k = 0; k < KM; ++k)
#pragma unroll
    for (int q = 0; q < 8; ++q) {
      float s = 0.0f;
#pragma unroll
      for (int l = 0; l < 8; ++l) {
        const bool kept = ISY ? keptY(k, l) : keptC(k, l);
        if (kept) s += Yv[k][l] * TBL.ID[q][l];
      }
      Uv[k][q] = s;
    }

#pragma unroll
  for (int p = 0; p < 8; ++p)          // Z = ID(:,0:KM) @ U, written back
#pragma unroll
    for (int q = 0; q < 8; ++q) {
      float s = 0.0f;
#pragma unroll
      for (int k = 0; k < KM; ++k) s += TBL.ID[p][k] * Uv[k][q];
      t[p * 8 + q] = s;
    }
}

__global__ __launch_bounds__(256) void jpeg_kernel(const float* __restrict__ in,
                                                   float* __restrict__ out) {
  __shared__ float lds[3 * CH];        // 49920 B -> 3 blocks/CU
  const int tid = threadIdx.x;
  const int blk = blockIdx.x;
  const int b  = blk >> 6;             // batch
  const int ti = blk & 63;             // 8-row strip index
  const size_t plane = (size_t)HEI * WID;
  const size_t base0 = (size_t)b * 3 * plane + (size_t)(ti * TIL) * WID;

  // ---- Pass A: coalesced float4 RGB loads -> YUV -> LDS (tile-major, pad 65)
#pragma unroll
  for (int it = 0; it < 4; ++it) {
    const int p4  = it * 256 + tid;    // pixel-quad 0..1023
    const int row = p4 >> 7;           // 0..7 (row within strip == row within tile)
    const int col = (p4 & 127) << 2;   // 0..508
    const size_t g = base0 + (size_t)row * WID + col;
    const float4 rq = *(const float4*)(in + g);
    const float4 gq = *(const float4*)(in + g + plane);
    const float4 bq = *(const float4*)(in + g + 2 * plane);
    const int off = (col >> 3) * LSTRIDE + row * 8 + (col & 7);
    const float rr[4] = {rq.x, rq.y, rq.z, rq.w};
    const float gg[4] = {gq.x, gq.y, gq.z, gq.w};
    const float bb[4] = {bq.x, bq.y, bq.z, bq.w};
#pragma unroll
    for (int j = 0; j < 4; ++j) {
      const float R = rr[j], G = gg[j], Bv = bb[j];
      lds[          off + j] =  0.299f   * R + 0.587f   * G + 0.114f   * Bv;
      lds[CH      + off + j] = -0.14713f * R - 0.28886f * G + 0.436f   * Bv;
      lds[2 * CH  + off + j] =  0.615f   * R - 0.51499f * G - 0.10001f * Bv;
    }
  }
  __syncthreads();

  // ---- Pass B: one thread per (channel, tile); channel is wave-uniform
  if (tid < 192) {
    const int c = tid >> 6;
    float* tp = lds + c * CH + (tid & 63) * LSTRIDE;
    if (c == 0) tile_transform<true>(tp);
    else        tile_transform<false>(tp);
  }
  __syncthreads();

  // ---- Pass C: YUV -> RGB, coalesced float4 stores
#pragma unroll
  for (int it = 0; it < 4; ++it) {
    const int p4  = it * 256 + tid;
    const int row = p4 >> 7;
    const int col = (p4 & 127) << 2;
    const int off = (col >> 3) * LSTRIDE + row * 8 + (col & 7);
    float4 ro, go, bo;
#pragma unroll
    for (int j = 0; j < 4; ++j) {
      const float Yy = lds[         off + j];
      const float Uu = lds[CH     + off + j];
      const float Vv = lds[2 * CH + off + j];
      (&ro.x)[j] = Yy + 1.13983f * Vv;
      (&go.x)[j] = Yy - 0.39465f * Uu - 0.5806f * Vv;
      (&bo.x)[j] = Yy + 2.03211f * Uu;
    }
    const size_t g = base0 + (size_t)row * WID + col;
    *(float4*)(out + g)             = ro;
    *(float4*)(out + g + plane)     = go;
    *(float4*)(out + g + 2 * plane) = bo;
  }
}

} // namespace

extern "C" void kernel_launch(void* const* d_in, const int* in_sizes, int n_in,
                              void* d_out, int out_size, void* d_ws, size_t ws_size,
                              hipStream_t stream) {
  const float* in = (const float*)d_in[0];
  float* out = (float*)d_out;
  jpeg_kernel<<<dim3(NB * (HEI / TIL)), dim3(256), 0, stream>>>(in, out);
}

// Round 3
// 97.321 us; speedup vs baseline: 1.0154x; 1.0154x over previous
//
#include <hip/hip_runtime.h>
#include <cstdint>
#include <cstddef>

namespace {

constexpr int TIL = 8;
constexpr int WID = 512;
constexpr int HEI = 512;
constexpr int NB  = 16;
constexpr int TPR = WID / TIL;        // 64 tiles per 8-row strip
constexpr int LSTRIDE = 66;           // even: tiles 8B-aligned; 2-way bank alias = free (m136)
constexpr int CH = TPR * LSTRIDE;     // 4224 floats per channel per strip

typedef float vf4 __attribute__((ext_vector_type(4)));   // nontemporal-store-compatible

// cos(t * pi/16) lookup, exact to fp32
constexpr float C16[17] = {
  1.0f, 0.9807852804032304f, 0.9238795325112867f, 0.8314696123025452f,
  0.7071067811865476f, 0.5555702330196022f, 0.3826834323650898f,
  0.1950903220161283f, 0.0f, -0.1950903220161283f, -0.3826834323650898f,
  -0.5555702330196022f, -0.7071067811865476f, -0.8314696123025452f,
  -0.9238795325112867f, -0.9807852804032304f, -1.0f
};

constexpr float cosp(int t) {         // cos(t*pi/16), any integer t
  int a = ((t % 32) + 32) % 32;
  return (a <= 16) ? C16[a] : C16[32 - a];
}

struct Tbl { float D[8][8]; float ID[8][8]; };

constexpr Tbl make_tbl() {
  Tbl t{};
  for (int k = 0; k < 8; ++k)
    for (int n = 0; n < 8; ++n) {
      t.D[k][n] = cosp((2 * n + 1) * k);          // cos(pi/8*(n+.5)*k)
      float v = cosp((2 * k + 1) * n);            // cos(pi/8*(k+.5)*n)
      if (n == 0) v -= 0.5f;
      t.ID[k][n] = v * 0.25f;                     // * sqrt(1/16)
    }
  return t;
}

constexpr Tbl TBL = make_tbl();

// zigzag keep masks: Y keeps 25, U/V keep 9 coefficients
constexpr bool keptY(int k, int l) { return (k + l <= 5) || (k + l == 6 && l <= 3); }
constexpr bool keptC(int k, int l) { return (k + l <= 2) || (k + l == 3 && k <= 2); }

// In-place 8x8: X -> ID @ (mask .* (D @ X @ D^T)) @ ID^T
// Register-lean: T rows die as Uv rows are born (peak live ~70 floats).
template <bool ISY>
__device__ __forceinline__ void tile_transform(float* __restrict__ t) {
  constexpr int KM = ISY ? 7 : 3;

  float T[KM][8];                      // T = D @ X, rows 0..KM-1
#pragma unroll
  for (int k = 0; k < KM; ++k)
#pragma unroll
    for (int m = 0; m < 8; ++m) T[k][m] = 0.0f;

#pragma unroll
  for (int n = 0; n < 8; ++n) {
    float x[8];
#pragma unroll
    for (int h = 0; h < 4; ++h) {      // 8B-aligned: tile base even, n*8 even
      const float2 v = ((const float2*)(t + n * 8))[h];
      x[2 * h] = v.x; x[2 * h + 1] = v.y;
    }
#pragma unroll
    for (int k = 0; k < KM; ++k) {
      const float d = TBL.D[k][n];
#pragma unroll
      for (int m = 0; m < 8; ++m) T[k][m] = __builtin_fmaf(d, x[m], T[k][m]);
    }
  }

  float Uv[KM][8];                     // Uv[k] = (mask_k .* (T[k] @ D^T)) @ ID^T
#pragma unroll
  for (int k = 0; k < KM; ++k) {
    float yv[8];
#pragma unroll
    for (int l = 0; l < 8; ++l) {
      if (ISY ? keptY(k, l) : keptC(k, l)) {
        float s = 0.0f;
#pragma unroll
        for (int m = 0; m < 8; ++m) s = __builtin_fmaf(T[k][m], TBL.D[l][m], s);
        yv[l] = s;
      }
    }
#pragma unroll
    for (int q = 0; q < 8; ++q) {
      float s = 0.0f;
#pragma unroll
      for (int l = 0; l < 8; ++l)
        if (ISY ? keptY(k, l) : keptC(k, l))
          s = __builtin_fmaf(yv[l], TBL.ID[q][l], s);
      Uv[k][q] = s;
    }
  }

#pragma unroll
  for (int p = 0; p < 8; ++p) {        // Z = ID(:,0:KM) @ Uv, written back
    float o[8];
#pragma unroll
    for (int q = 0; q < 8; ++q) {
      float s = 0.0f;
#pragma unroll
      for (int k = 0; k < KM; ++k) s = __builtin_fmaf(TBL.ID[p][k], Uv[k][q], s);
      o[q] = s;
    }
#pragma unroll
    for (int h = 0; h < 4; ++h)
      ((float2*)(t + p * 8))[h] = make_float2(o[2 * h], o[2 * h + 1]);
  }
}

__global__ __launch_bounds__(256) void jpeg_kernel(const float* __restrict__ in,
                                                   float* __restrict__ out) {
  __shared__ float lds[3 * CH];        // 50688 B -> 3 blocks/CU (LDS-capped)
  const int tid = threadIdx.x;
  const int blk = blockIdx.x;
  const int b  = blk >> 6;             // batch
  const int ti = blk & 63;             // 8-row strip index
  const size_t plane = (size_t)HEI * WID;
  const size_t base0 = (size_t)b * 3 * plane + (size_t)(ti * TIL) * WID;

  // ---- Pass A: batch-issue all 12 float4 loads, then YUV -> LDS
  float4 rq[4], gq[4], bq[4];
  int offv[4];
#pragma unroll
  for (int it = 0; it < 4; ++it) {
    const int p4  = it * 256 + tid;    // pixel-quad 0..1023
    const int row = p4 >> 7;           // 0..7
    const int col = (p4 & 127) << 2;   // 0..508, %4==0
    const size_t g = base0 + (size_t)row * WID + col;
    rq[it] = *(const float4*)(in + g);
    gq[it] = *(const float4*)(in + g + plane);
    bq[it] = *(const float4*)(in + g + 2 * plane);
    offv[it] = (col >> 3) * LSTRIDE + row * 8 + (col & 7);   // even
  }
#pragma unroll
  for (int it = 0; it < 4; ++it) {
    const float rr[4] = {rq[it].x, rq[it].y, rq[it].z, rq[it].w};
    const float gg[4] = {gq[it].x, gq[it].y, gq[it].z, gq[it].w};
    const float bb[4] = {bq[it].x, bq[it].y, bq[it].z, bq[it].w};
    float y[4], u[4], v[4];
#pragma unroll
    for (int j = 0; j < 4; ++j) {
      const float R = rr[j], G = gg[j], Bv = bb[j];
      y[j] =  0.299f   * R + 0.587f   * G + 0.114f   * Bv;
      u[j] = -0.14713f * R - 0.28886f * G + 0.436f   * Bv;
      v[j] =  0.615f   * R - 0.51499f * G - 0.10001f * Bv;
    }
    const int off = offv[it];
    ((float2*)(lds + off))[0]          = make_float2(y[0], y[1]);
    ((float2*)(lds + off))[1]          = make_float2(y[2], y[3]);
    ((float2*)(lds + CH + off))[0]     = make_float2(u[0], u[1]);
    ((float2*)(lds + CH + off))[1]     = make_float2(u[2], u[3]);
    ((float2*)(lds + 2 * CH + off))[0] = make_float2(v[0], v[1]);
    ((float2*)(lds + 2 * CH + off))[1] = make_float2(v[2], v[3]);
  }
  __syncthreads();

  // ---- Pass B: one thread per (channel, tile); channel is wave-uniform
  if (tid < 192) {
    const int c = tid >> 6;
    float* tp = lds + c * CH + (tid & 63) * LSTRIDE;
    if (c == 0) tile_transform<true>(tp);
    else        tile_transform<false>(tp);
  }
  __syncthreads();

  // ---- Pass C: YUV -> RGB, coalesced nontemporal float4 stores
#pragma unroll
  for (int it = 0; it < 4; ++it) {
    const int p4  = it * 256 + tid;
    const int row = p4 >> 7;
    const int col = (p4 & 127) << 2;
    const int off = (col >> 3) * LSTRIDE + row * 8 + (col & 7);
    vf4 ro, go, bo;
#pragma unroll
    for (int h = 0; h < 2; ++h) {
      const float2 yy = ((const float2*)(lds + off))[h];
      const float2 uu = ((const float2*)(lds + CH + off))[h];
      const float2 vv = ((const float2*)(lds + 2 * CH + off))[h];
      ro[2 * h]     = yy.x + 1.13983f * vv.x;
      ro[2 * h + 1] = yy.y + 1.13983f * vv.y;
      go[2 * h]     = yy.x - 0.39465f * uu.x - 0.5806f * vv.x;
      go[2 * h + 1] = yy.y - 0.39465f * uu.y - 0.5806f * vv.y;
      bo[2 * h]     = yy.x + 2.03211f * uu.x;
      bo[2 * h + 1] = yy.y + 2.03211f * uu.y;
    }
    const size_t g = base0 + (size_t)row * WID + col;
    __builtin_nontemporal_store(ro, (vf4*)(out + g));
    __builtin_nontemporal_store(go, (vf4*)(out + g + plane));
    __builtin_nontemporal_store(bo, (vf4*)(out + g + 2 * plane));
  }
}

} // namespace

extern "C" void kernel_launch(void* const* d_in, const int* in_sizes, int n_in,
                              void* d_out, int out_size, void* d_ws, size_t ws_size,
                              hipStream_t stream) {
  const float* in = (const float*)d_in[0];
  float* out = (float*)d_out;
  jpeg_kernel<<<dim3(NB * (HEI / TIL)), dim3(256), 0, stream>>>(in, out);
}